// Round 7
// baseline (1019.427 us; speedup 1.0000x reference)
//
#include <hip/hip_runtime.h>
#include <math.h>

// Problem constants
#define NN 150   // nodes
#define BB 32    // batch
#define TT 8     // time
#define FF 16    // input features
#define HH 32    // hidden
#define ROWS (NN*BB)     // 4800 (row index = n*32 + b)
#define NCIN (BB*FF)     // 512
#define NCH  (BB*HH)     // 1024
#define ADJ_LD 160       // padded adjacency row stride (zero-filled 150..159)
#define PS_LD 65         // fusedA Ps k-stride in float4 units

// workspace sizes (floats)
#define SZ_ADJF (4*NN*ADJ_LD)
#define SZ_WA0  (4*48*32*4)   // packed [c][48][32][4]
#define SZ_WA1  (4*64*32*4)   // packed [c][64][32][4]
#define SZ_WB   (32*32*4)     // packed [k][o][c]
#define SZ_STATE (ROWS*HH*4)  // 614400 ; also = partial stride 4*NN*NCH
#define SZ_PIN  (4*NN*NCIN)   // 307200 ; partial stride of input agg

__device__ __forceinline__ float sigmoidf_(float x){ return 1.f/(1.f+expf(-x)); }

__device__ __forceinline__ float comp_of4(float x0, float x1, float x2, float x3, int c) {
  return c==0 ? (x0+x1+x2+x3) : c==1 ? (x0-x2) : c==2 ? (x3-x1) : (x0-x1+x2-x3);
}

// Fourier comps of a real length-4 tube: c0, c1re, c1im, c2 (face3 = conj(face1))
// ifft: y0=(c0+2c1re+c2)/4; y1=(c0-2c1im-c2)/4; y2=(c0-2c1re+c2)/4; y3=(c0+2c1im-c2)/4

// ---------------- pre: adjacency (blocks 0..149) + packed weights ----------------
__global__ __launch_bounds__(256) void k_pre(
    const float* __restrict__ U, float* __restrict__ adjF,
    const float* __restrict__ Wxz0, const float* __restrict__ Wxr0, const float* __restrict__ Wxh0,
    const float* __restrict__ Whz0, const float* __restrict__ Whr0,
    const float* __restrict__ Wxz1, const float* __restrict__ Wxr1, const float* __restrict__ Wxh1,
    const float* __restrict__ Whz1, const float* __restrict__ Whr1,
    float* __restrict__ WA0p, float* __restrict__ WA1p,
    float* __restrict__ WB0p, float* __restrict__ WB1p) {
  __shared__ float Ufl[NN*16*4];
  __shared__ float Arow[NN*4];
  __shared__ float red[256];
  __shared__ float mxs[4], isms[4];
  int tid = threadIdx.x;
  if (blockIdx.x < NN) {
    int n = blockIdx.x;
    for (int idx = tid; idx < NN*16; idx += 256) {
      const float* s = U + (size_t)idx*4;
      float x0=s[0], x1=s[1], x2=s[2], x3=s[3];
      Ufl[idx*4+0] = x0+x1+x2+x3;
      Ufl[idx*4+1] = x0-x2;
      Ufl[idx*4+2] = x3-x1;
      Ufl[idx*4+3] = x0-x1+x2-x3;
    }
    __syncthreads();
    if (tid < NN) {
      int m = tid;
      float a0=0, ar=0, ai=0, a2=0;
      #pragma unroll
      for (int e = 0; e < 16; ++e) {
        const float* un = &Ufl[(n*16+e)*4];
        const float* um = &Ufl[(m*16+e)*4];
        a0 += un[0]*um[0];
        ar += un[1]*um[1] - un[2]*um[2];
        ai += un[1]*um[2] + un[2]*um[1];
        a2 += un[3]*um[3];
      }
      float r0 = 0.25f*(a0 + 2.f*ar + a2);
      float r1 = 0.25f*(a0 - 2.f*ai - a2);
      float r2 = 0.25f*(a0 - 2.f*ar + a2);
      float r3 = 0.25f*(a0 + 2.f*ai - a2);
      Arow[m*4+0] = fmaxf(r0, 0.f);
      Arow[m*4+1] = fmaxf(r1, 0.f);
      Arow[m*4+2] = fmaxf(r2, 0.f);
      Arow[m*4+3] = fmaxf(r3, 0.f);
    }
    __syncthreads();
    for (int r = 0; r < 4; ++r) {
      float v = (tid < NN) ? Arow[tid*4+r] : -1e30f;
      red[tid] = v; __syncthreads();
      for (int s = 128; s > 0; s >>= 1) { if (tid < s) red[tid] = fmaxf(red[tid], red[tid+s]); __syncthreads(); }
      if (tid == 0) mxs[r] = red[0];
      __syncthreads();
      float e = (tid < NN) ? expf(Arow[tid*4+r] - mxs[r]) : 0.f;
      red[tid] = e; __syncthreads();
      for (int s = 128; s > 0; s >>= 1) { if (tid < s) red[tid] += red[tid+s]; __syncthreads(); }
      if (tid == 0) isms[r] = 1.f / red[0];
      __syncthreads();
      if (tid < NN) Arow[tid*4+r] = e * isms[r];
      __syncthreads();
    }
    if (tid < NN) {
      int m = tid;
      float e0=Arow[m*4+0], e1=Arow[m*4+1], e2=Arow[m*4+2], e3=Arow[m*4+3];
      size_t base = (size_t)n*ADJ_LD + m;
      size_t cs = (size_t)NN*ADJ_LD;
      adjF[base]      = e0+e1+e2+e3;
      adjF[base+cs]   = e0-e2;
      adjF[base+2*cs] = e3-e1;
      adjF[base+3*cs] = e0-e1+e2-e3;
    } else if (tid < ADJ_LD) {
      size_t base = (size_t)n*ADJ_LD + tid;
      size_t cs = (size_t)NN*ADJ_LD;
      adjF[base] = 0.f; adjF[base+cs] = 0.f; adjF[base+2*cs] = 0.f; adjF[base+3*cs] = 0.f;
    }
    return;
  }
  int idx = (blockIdx.x - NN)*256 + tid;
  const float* src = nullptr;
  float* dst; int didx; int c;
  if (idx < SZ_WA0) {
    c = idx / 6144;
    int rem = idx % 6144;
    int k = rem >> 7, og = (rem >> 2) & 31, q = rem & 3;
    if (q == 0) src = (k < FF) ? Wxz0 + ((size_t)k*HH + og)*4 : Whz0 + ((size_t)(k-FF)*HH + og)*4;
    else if (q == 1) src = (k < FF) ? Wxr0 + ((size_t)k*HH + og)*4 : Whr0 + ((size_t)(k-FF)*HH + og)*4;
    else if (q == 2 && k < FF) src = Wxh0 + ((size_t)k*HH + og)*4;
    dst = WA0p; didx = idx;
  } else if (idx < SZ_WA0 + SZ_WA1) {
    int id = idx - SZ_WA0;
    c = id >> 13;
    int rem = id & 8191;
    int k = rem >> 7, og = (rem >> 2) & 31, q = rem & 3;
    if (q == 0) src = (k < HH) ? Wxz1 + ((size_t)k*HH + og)*4 : Whz1 + ((size_t)(k-HH)*HH + og)*4;
    else if (q == 1) src = (k < HH) ? Wxr1 + ((size_t)k*HH + og)*4 : Whr1 + ((size_t)(k-HH)*HH + og)*4;
    else if (q == 2 && k < HH) src = Wxh1 + ((size_t)k*HH + og)*4;
    dst = WA1p; didx = id;
  } else if (idx < SZ_WA0 + SZ_WA1 + SZ_WB) {
    int id = idx - (SZ_WA0 + SZ_WA1);
    int k = id >> 7, o = (id >> 2) & 31;
    c = id & 3;
    src = Whr0 + ((size_t)k*HH + o)*4;
    dst = WB0p; didx = id;
  } else if (idx < SZ_WA0 + SZ_WA1 + 2*SZ_WB) {
    int id = idx - (SZ_WA0 + SZ_WA1 + SZ_WB);
    int k = id >> 7, o = (id >> 2) & 31;
    c = id & 3;
    src = Whr1 + ((size_t)k*HH + o)*4;
    dst = WB1p; didx = id;
  } else return;
  float v0=0,v1=0,v2=0,v3=0;
  if (src) { v0=src[0]; v1=src[1]; v2=src[2]; v3=src[3]; }
  dst[didx] = comp_of4(v0,v1,v2,v3,c);
}

// ---------------- round-6 agg body (split-K, used for PIN precompute + t0) ----------------
template<bool RAW>
__device__ __forceinline__ void agg_body(const float* __restrict__ adjF,
                                         const float* __restrict__ X,
                                         const float* __restrict__ inp,
                                         float* __restrict__ P, int ncol,
                                         int tile, int part, int rawt,
                                         float* As, float* Xs, int tid) {
  int kbeg = part ? 96 : 0;
  int kend = part ? NN : 96;
  int n0 = (tile % 5) * 32;
  int col0 = (tile / 5) * 32;
  int ti = tid & 31, tj = tid >> 5;
  int j0 = tj * 4;
  float a0[4]={}, aR[4]={}, aI[4]={}, a2v[4]={};
  float4 pa[4], px[4];

  #define LOAD_A(K0)                                                         \
    _Pragma("unroll")                                                        \
    for (int u = 0; u < 4; ++u) {                                            \
      int e = tid + u*256;                                                   \
      int c = e >> 8, rem = e & 255, i = rem >> 3, kq = rem & 7;             \
      int nn_ = n0 + i;                                                      \
      pa[u] = make_float4(0,0,0,0);                                          \
      if (nn_ < NN) pa[u] = *(const float4*)(adjF + ((size_t)c*NN + nn_)*ADJ_LD + (K0) + kq*4); \
    }
  #define STORE_A()                                                          \
    _Pragma("unroll")                                                        \
    for (int u = 0; u < 4; ++u) {                                            \
      int e = tid + u*256;                                                   \
      int c = e >> 8, rem = e & 255, i = rem >> 3, kq = rem & 7;             \
      As[((kq*4+0)*33 + i)*4 + c] = pa[u].x;                                 \
      As[((kq*4+1)*33 + i)*4 + c] = pa[u].y;                                 \
      As[((kq*4+2)*33 + i)*4 + c] = pa[u].z;                                 \
      As[((kq*4+3)*33 + i)*4 + c] = pa[u].w;                                 \
    }
  #define LOAD_X(K0)                                                         \
    if (RAW) {                                                               \
      int q = tid & 7, kk = tid >> 3;                                        \
      int mm = (K0) + kk;                                                    \
      int col = col0 + q*4;                                                  \
      int b = col >> 4, f = col & 15;                                        \
      px[0]=px[1]=px[2]=px[3]=make_float4(0,0,0,0);                          \
      if (mm < NN) {                                                         \
        const float* s = inp + (((size_t)(b*TT + rawt)*NN + mm)*FF + f)*4;   \
        px[0] = *(const float4*)(s+0);                                       \
        px[1] = *(const float4*)(s+4);                                       \
        px[2] = *(const float4*)(s+8);                                       \
        px[3] = *(const float4*)(s+12);                                      \
      }                                                                      \
    } else {                                                                 \
      _Pragma("unroll")                                                      \
      for (int u = 0; u < 4; ++u) {                                          \
        int e = tid + u*256;                                                 \
        int c = e >> 8, rem = e & 255, kk = rem >> 3, q = rem & 7;           \
        int mm = (K0) + kk;                                                  \
        px[u] = make_float4(0,0,0,0);                                        \
        if (mm < NN) px[u] = *(const float4*)(X + ((size_t)c*NN + mm)*ncol + col0 + q*4); \
      }                                                                      \
    }
  #define STORE_X()                                                          \
    if (RAW) {                                                               \
      int q = tid & 7, kk = tid >> 3;                                        \
      float4 r0 = px[0], r1 = px[1], r2 = px[2], r3 = px[3];                 \
      float4 w;                                                              \
      w = make_float4(r0.x+r0.y+r0.z+r0.w, r1.x+r1.y+r1.z+r1.w, r2.x+r2.y+r2.z+r2.w, r3.x+r3.y+r3.z+r3.w); \
      *(float4*)&Xs[(0*32+kk)*36 + q*4] = w;                                 \
      w = make_float4(r0.x-r0.z, r1.x-r1.z, r2.x-r2.z, r3.x-r3.z);           \
      *(float4*)&Xs[(1*32+kk)*36 + q*4] = w;                                 \
      w = make_float4(r0.w-r0.y, r1.w-r1.y, r2.w-r2.y, r3.w-r3.y);           \
      *(float4*)&Xs[(2*32+kk)*36 + q*4] = w;                                 \
      w = make_float4(r0.x-r0.y+r0.z-r0.w, r1.x-r1.y+r1.z-r1.w, r2.x-r2.y+r2.z-r2.w, r3.x-r3.y+r3.z-r3.w); \
      *(float4*)&Xs[(3*32+kk)*36 + q*4] = w;                                 \
    } else {                                                                 \
      _Pragma("unroll")                                                      \
      for (int u = 0; u < 4; ++u) {                                          \
        int e = tid + u*256;                                                 \
        int c = e >> 8, rem = e & 255, kk = rem >> 3, q = rem & 7;           \
        *(float4*)&Xs[(c*32+kk)*36 + q*4] = px[u];                           \
      }                                                                      \
    }

  LOAD_A(kbeg)
  LOAD_X(kbeg)
  for (int k0 = kbeg; k0 < kend; k0 += 32) {
    STORE_A()
    STORE_X()
    __syncthreads();
    int k0n = k0 + 32;
    if (k0n < kend) {
      LOAD_A(k0n)
      LOAD_X(k0n)
    }
    #pragma unroll 4
    for (int k = 0; k < 32; ++k) {
      float4 a4 = *(float4*)&As[(k*33 + ti)*4];
      float4 x0 = *(float4*)&Xs[(0*32+k)*36 + j0];
      float4 x1 = *(float4*)&Xs[(1*32+k)*36 + j0];
      float4 x2 = *(float4*)&Xs[(2*32+k)*36 + j0];
      float4 x3 = *(float4*)&Xs[(3*32+k)*36 + j0];
      float X0v[4]={x0.x,x0.y,x0.z,x0.w}, X1v[4]={x1.x,x1.y,x1.z,x1.w};
      float X2v[4]={x2.x,x2.y,x2.z,x2.w}, X3v[4]={x3.x,x3.y,x3.z,x3.w};
      #pragma unroll
      for (int j = 0; j < 4; ++j) {
        a0[j]  += a4.x*X0v[j];
        aR[j]  += a4.y*X1v[j] - a4.z*X2v[j];
        aI[j]  += a4.y*X2v[j] + a4.z*X1v[j];
        a2v[j] += a4.w*X3v[j];
      }
    }
    __syncthreads();
  }
  #undef LOAD_A
  #undef STORE_A
  #undef LOAD_X
  #undef STORE_X
  int nn_ = n0 + ti;
  if (nn_ < NN) {
    size_t cs = (size_t)NN*ncol;
    size_t rb = (size_t)nn_*ncol + col0 + j0;
    *(float4*)&P[rb]      = make_float4(a0[0],a0[1],a0[2],a0[3]);
    *(float4*)&P[rb+cs]   = make_float4(aR[0],aR[1],aR[2],aR[3]);
    *(float4*)&P[rb+2*cs] = make_float4(aI[0],aI[1],aI[2],aI[3]);
    *(float4*)&P[rb+3*cs] = make_float4(a2v[0],a2v[1],a2v[2],a2v[3]);
  }
}

#define AGG_AS 4224   // 32*33*4
#define AGG_XS 4608   // 4*32*36

// input aggregation for ALL timesteps (split-K 2 parts)
__global__ __launch_bounds__(256,4) void k_aggIN(const float* __restrict__ adjF,
                                                 const float* __restrict__ inp,
                                                 float* __restrict__ PIN) {
  __shared__ float As[AGG_AS];
  __shared__ float Xs[AGG_XS];
  int u = blockIdx.x;              // [8 t][2 part][80 tiles]
  int t = u / 160, rem = u % 160, part = rem / 80, tile = rem % 80;
  float* P = PIN + (size_t)t*2*SZ_PIN + (size_t)part*SZ_PIN;
  agg_body<true>(adjF, nullptr, inp, P, NCIN, tile, part, t, As, Xs, threadIdx.x);
}

// t0 hidden aggregation (1 job, split-K 2 parts)
struct AggParams {
  const float* X0; float* P0; int nb;
};
__global__ __launch_bounds__(256,4) void k_agg(AggParams pr, const float* __restrict__ adjF) {
  __shared__ float As[AGG_AS];
  __shared__ float Xs[AGG_XS];
  int bid = blockIdx.x;
  int part = (bid >= pr.nb) ? 1 : 0;
  if (part) bid -= pr.nb;
  float* P = pr.P0 + (size_t)part * SZ_STATE;
  agg_body<false>(adjF, pr.X0, nullptr, P, NCH, bid, part, -1, As, Xs, threadIdx.x);
}

// ---------------- round-6 fusedA (t0 only) ----------------
struct FAJob {
  const float* Px; const float* Ph; const float* W; const float* bias;
  const float* hprev;
  float* Z; float* T1; float* Mf;
  int zh;
};
struct FAParams { FAJob j[2]; };

template<int KTOT, int KX>
__device__ __forceinline__ void fusedA_body(const FAJob& jb, float* Ps, float* Ws) {
  const int row0 = blockIdx.x * 16;
  const int tid = threadIdx.x;
  const int og = tid & 31;
  const int rg = tid >> 5;
  const int r0 = rg*2, r1 = rg*2 + 1;
  const size_t psx = (size_t)4*ROWS*KX;
  const size_t psh = (size_t)4*ROWS*HH;
  constexpr int K4 = KTOT/4;
  for (int e = tid; e < 16*4*K4; e += 256) {
    int k4 = e % K4; int c = (e / K4) & 3; int r = e / (K4*4);
    int k = k4*4;
    int row = row0 + r;
    float4 v;
    if (k < KX) {
      const float* a = &jb.Px[((size_t)c*ROWS + row)*KX + k];
      float4 va = *(const float4*)a;
      float4 vb = *(const float4*)(a + psx);
      v = make_float4(va.x+vb.x, va.y+vb.y, va.z+vb.z, va.w+vb.w);
    } else if (jb.zh) {
      v = make_float4(0,0,0,0);
    } else {
      const float* a = &jb.Ph[((size_t)c*ROWS + row)*HH + (k - KX)];
      float4 va = *(const float4*)a;
      float4 vb = *(const float4*)(a + psh);
      v = make_float4(va.x+vb.x, va.y+vb.y, va.z+vb.z, va.w+vb.w);
    }
    Ps[(r*PS_LD + k+0)*4 + c] = v.x;
    Ps[(r*PS_LD + k+1)*4 + c] = v.y;
    Ps[(r*PS_LD + k+2)*4 + c] = v.z;
    Ps[(r*PS_LD + k+3)*4 + c] = v.w;
  }
  float acc0[2][3]={{0,0,0},{0,0,0}}, accR[2][3]={{0,0,0},{0,0,0}};
  float accI[2][3]={{0,0,0},{0,0,0}}, acc2[2][3]={{0,0,0},{0,0,0}};
  constexpr int NCHK = KTOT/16;
  const float4* Wg = (const float4*)jb.W;
  for (int cc = 0; cc < NCHK; ++cc) {
    __syncthreads();
    #pragma unroll
    for (int u = 0; u < 8; ++u) {
      int f = tid + u*256;
      int c = f >> 9, rem = f & 511;
      float4 v = Wg[((size_t)c*KTOT + cc*16)*32 + rem];
      *(float4*)&Ws[((size_t)c*512 + rem)*4] = v;
    }
    __syncthreads();
    #pragma unroll 4
    for (int kk = 0; kk < 16; ++kk) {
      int k = cc*16 + kk;
      float4 pA = *(float4*)&Ps[(r0*PS_LD + k)*4];
      float4 pB = *(float4*)&Ps[(r1*PS_LD + k)*4];
      float4 w0 = *(float4*)&Ws[((0*16+kk)*32+og)*4];
      float4 w1 = *(float4*)&Ws[((1*16+kk)*32+og)*4];
      float4 w2 = *(float4*)&Ws[((2*16+kk)*32+og)*4];
      float4 w3 = *(float4*)&Ws[((3*16+kk)*32+og)*4];
      float W0v[3]={w0.x,w0.y,w0.z}, W1v[3]={w1.x,w1.y,w1.z};
      float W2v[3]={w2.x,w2.y,w2.z}, W3v[3]={w3.x,w3.y,w3.z};
      #pragma unroll
      for (int q = 0; q < 3; ++q) {
        acc0[0][q] += pA.x*W0v[q];
        acc0[1][q] += pB.x*W0v[q];
        accR[0][q] += pA.y*W1v[q] - pA.z*W2v[q];
        accR[1][q] += pB.y*W1v[q] - pB.z*W2v[q];
        accI[0][q] += pA.y*W2v[q] + pA.z*W1v[q];
        accI[1][q] += pB.y*W2v[q] + pB.z*W1v[q];
        acc2[0][q] += pA.w*W3v[q];
        acc2[1][q] += pB.w*W3v[q];
      }
    }
  }
  const float* bz = jb.bias + (0*HH + og)*4;
  const float* br = jb.bias + (1*HH + og)*4;
  const float* bh = jb.bias + (2*HH + og)*4;
  float bzv[4] = {bz[0],bz[1],bz[2],bz[3]};
  float brv[4] = {br[0],br[1],br[2],br[3]};
  float bhv[4] = {bh[0],bh[1],bh[2],bh[3]};
  #pragma unroll
  for (int rr = 0; rr < 2; ++rr) {
    int row = row0 + rg*2 + rr;
    float ys[3][4];
    #pragma unroll
    for (int q = 0; q < 3; ++q) {
      float Y0 = acc0[rr][q], Yr = accR[rr][q], Yi = accI[rr][q], Y2 = acc2[rr][q];
      ys[q][0] = 0.25f*(Y0 + 2.f*Yr + Y2);
      ys[q][1] = 0.25f*(Y0 - 2.f*Yi - Y2);
      ys[q][2] = 0.25f*(Y0 - 2.f*Yr + Y2);
      ys[q][3] = 0.25f*(Y0 + 2.f*Yi - Y2);
    }
    float4 z = make_float4(sigmoidf_(ys[0][0]+bzv[0]), sigmoidf_(ys[0][1]+bzv[1]),
                           sigmoidf_(ys[0][2]+bzv[2]), sigmoidf_(ys[0][3]+bzv[3]));
    *(float4*)&jb.Z[((size_t)row*HH + og)*4] = z;
    float4 hp = make_float4(0,0,0,0);
    if (!jb.zh) hp = *(const float4*)&jb.hprev[((size_t)row*HH + og)*4];
    float m0 = sigmoidf_(ys[1][0]+brv[0]) * hp.x;
    float m1 = sigmoidf_(ys[1][1]+brv[1]) * hp.y;
    float m2 = sigmoidf_(ys[1][2]+brv[2]) * hp.z;
    float m3 = sigmoidf_(ys[1][3]+brv[3]) * hp.w;
    size_t mb = (size_t)row*HH + og;
    size_t cs = (size_t)ROWS*HH;
    jb.Mf[mb]      = m0+m1+m2+m3;
    jb.Mf[mb+cs]   = m0-m2;
    jb.Mf[mb+2*cs] = m3-m1;
    jb.Mf[mb+3*cs] = m0-m1+m2-m3;
    float4 tv = make_float4(ys[2][0]+bhv[0], ys[2][1]+bhv[1], ys[2][2]+bhv[2], ys[2][3]+bhv[3]);
    *(float4*)&jb.T1[((size_t)row*HH + og)*4] = tv;
  }
}

#define FA_PS (16*PS_LD*4)

__global__ __launch_bounds__(256,3) void k_fusedA_L0(FAParams pr) {
  __shared__ float Ps[FA_PS];
  __shared__ float Ws[8192];
  fusedA_body<48,16>(pr.j[0], Ps, Ws);
}
__global__ __launch_bounds__(256,3) void k_fusedA_L1(FAParams pr) {
  __shared__ float Ps[FA_PS];
  __shared__ float Ws[8192];
  fusedA_body<64,32>(pr.j[1], Ps, Ws);
}

// ---------------- round-6 fusedB (t0 only, zh=1) ----------------
struct FBJob {
  const float* Pm; const float* W; const float* T1; const float* Z;
  float* h; float* hf; float* outp; float* hlast;
  int t, zh, wout;
};
struct FBParams { FBJob j[2]; };
__global__ __launch_bounds__(256,4) void k_fusedB(FBParams pr) {
  __shared__ float Ps[16*32*4];
  __shared__ float Ws[32*32*4];
  FBJob jb = pr.j[blockIdx.y];
  int row0 = blockIdx.x * 16;
  int tid = threadIdx.x;
  int rg = tid >> 5, o = tid & 31;
  int r0 = rg*2, r1 = r0 + 1;
  float acc0[2]={0,0}, accR[2]={0,0}, accI[2]={0,0}, acc2[2]={0,0};
  if (!jb.zh) {
    #pragma unroll
    for (int u = 0; u < 4; ++u) {
      int f = tid + u*256;
      ((float4*)Ws)[f] = ((const float4*)jb.W)[f];
    }
    const size_t psh = (size_t)4*ROWS*HH;
    #pragma unroll
    for (int u = 0; u < 2; ++u) {
      int e = tid + u*256;
      int r = e >> 5, k = e & 31;
      int row = row0 + r;
      float4 v;
      float* vv = (float*)&v;
      #pragma unroll
      for (int c = 0; c < 4; ++c) {
        size_t ix = ((size_t)c*ROWS + row)*HH + k;
        vv[c] = jb.Pm[ix] + jb.Pm[ix + psh];
      }
      *(float4*)&Ps[(r*32 + k)*4] = v;
    }
    __syncthreads();
    #pragma unroll 8
    for (int k = 0; k < 32; ++k) {
      float4 pA = *(const float4*)&Ps[(r0*32 + k)*4];
      float4 pB = *(const float4*)&Ps[(r1*32 + k)*4];
      float4 w  = *(const float4*)&Ws[(k*32 + o)*4];
      acc0[0] += pA.x*w.x;  acc0[1] += pB.x*w.x;
      accR[0] += pA.y*w.y - pA.z*w.z;  accR[1] += pB.y*w.y - pB.z*w.z;
      accI[0] += pA.y*w.z + pA.z*w.y;  accI[1] += pB.y*w.z + pB.z*w.y;
      acc2[0] += pA.w*w.w;  acc2[1] += pB.w*w.w;
    }
  }
  #pragma unroll
  for (int rr = 0; rr < 2; ++rr) {
    int row = row0 + rg*2 + rr;
    float y0 = 0.25f*(acc0[rr] + 2.f*accR[rr] + acc2[rr]);
    float y1 = 0.25f*(acc0[rr] - 2.f*accI[rr] - acc2[rr]);
    float y2 = 0.25f*(acc0[rr] - 2.f*accR[rr] + acc2[rr]);
    float y3 = 0.25f*(acc0[rr] + 2.f*accI[rr] - acc2[rr]);
    float4 t1 = *(const float4*)&jb.T1[((size_t)row*HH + o)*4];
    float h0v = tanhf(t1.x + y0);
    float h1v = tanhf(t1.y + y1);
    float h2v = tanhf(t1.z + y2);
    float h3v = tanhf(t1.w + y3);
    float4 z = *(const float4*)&jb.Z[((size_t)row*HH + o)*4];
    float4 hp = make_float4(0,0,0,0);
    if (!jb.zh) hp = *(const float4*)&jb.h[((size_t)row*HH + o)*4];
    float n0v = z.x*hp.x + (1.f-z.x)*h0v;
    float n1v = z.y*hp.y + (1.f-z.y)*h1v;
    float n2v = z.z*hp.z + (1.f-z.z)*h2v;
    float n3v = z.w*hp.w + (1.f-z.w)*h3v;
    *(float4*)&jb.h[((size_t)row*HH + o)*4] = make_float4(n0v,n1v,n2v,n3v);
    size_t hb = (size_t)row*HH + o, cs = (size_t)ROWS*HH;
    jb.hf[hb]      = n0v+n1v+n2v+n3v;
    jb.hf[hb+cs]   = n0v-n2v;
    jb.hf[hb+2*cs] = n3v-n1v;
    jb.hf[hb+3*cs] = n0v-n1v+n2v-n3v;
    int n = row >> 5, b = row & 31;
    if (jb.wout) {
      float* dst = jb.outp + (((size_t)b*TT + jb.t)*NN + n)*(HH*4) + o*4;
      *(float4*)dst = make_float4(n0v,n1v,n2v,n3v);
    }
    if (jb.hlast) {
      float* dst = jb.hlast + ((size_t)(b*NN + n))*(HH*4) + o*4;
      *(float4*)dst = make_float4(n0v,n1v,n2v,n3v);
    }
  }
}

// ================= fused step kernels (t >= 1) =================
// Block = (16 nodes, 1 batch). smem 11392 floats (45.6 KB).
// Agg phase: As[32k][17n][4c] @0 (2176); Xs0 @2176 (4608); Xs1 @6784 (4608).
// After agg:  PsH0/PsM0 @0 (2112) [16n][33h][4c]; PsH1/PsM1 @2112 (2112);
//             (step1) PsIN @4224 (1024) [16n][16f][4c]; Ws @5248 (4096).
//             (step2) Ws @4224 (4096).
#define SMEM_STEP 11392

__device__ __forceinline__ void step_agg(const float* __restrict__ adjF,
    const float* __restrict__ X0g, const float* __restrict__ X1g,
    int n0, int b, int tid, float* smem) {
  float* As  = smem;
  float* Xs0 = smem + 2176;
  float* Xs1 = smem + 6784;
  int an = tid & 15, hg = (tid >> 4) & 7, job = tid >> 7;
  int h0 = hg * 4;
  const float* Xsj = job ? Xs1 : Xs0;
  float a0[4]={}, aR[4]={}, aI[4]={}, a2[4]={};
  float4 pa[2], px[8];

  #define SLOAD(K0)                                                          \
    { _Pragma("unroll") for (int u = 0; u < 2; ++u) {                        \
        int e = tid + u*256;                                                 \
        int c = e >> 7, rem = e & 127, i = rem >> 3, kq = rem & 7;           \
        int nn_ = n0 + i;                                                    \
        pa[u] = make_float4(0,0,0,0);                                        \
        if (nn_ < NN) pa[u] = *(const float4*)(adjF + ((size_t)c*NN + nn_)*ADJ_LD + (K0) + kq*4); \
      }                                                                      \
      _Pragma("unroll") for (int u = 0; u < 8; ++u) {                        \
        int e = tid + u*256;                                                 \
        int jj = e >> 10, rem = e & 1023, c = rem >> 8, rem2 = rem & 255;    \
        int kk = rem2 >> 3, q = rem2 & 7;                                    \
        int m = (K0) + kk;                                                   \
        const float* Xg = jj ? X1g : X0g;                                    \
        px[u] = make_float4(0,0,0,0);                                       \
        if (m < NN) px[u] = *(const float4*)(Xg + ((size_t)c*NN + m)*NCH + b*32 + q*4); \
      } }
  #define SSTORE()                                                           \
    { _Pragma("unroll") for (int u = 0; u < 2; ++u) {                        \
        int e = tid + u*256;                                                 \
        int c = e >> 7, rem = e & 127, i = rem >> 3, kq = rem & 7;           \
        As[((kq*4+0)*17 + i)*4 + c] = pa[u].x;                               \
        As[((kq*4+1)*17 + i)*4 + c] = pa[u].y;                               \
        As[((kq*4+2)*17 + i)*4 + c] = pa[u].z;                               \
        As[((kq*4+3)*17 + i)*4 + c] = pa[u].w;                               \
      }                                                                      \
      _Pragma("unroll") for (int u = 0; u < 8; ++u) {                        \
        int e = tid + u*256;                                                 \
        int jj = e >> 10, rem = e & 1023, c = rem >> 8, rem2 = rem & 255;    \
        int kk = rem2 >> 3, q = rem2 & 7;                                    \
        float* Xsd = jj ? Xs1 : Xs0;                                         \
        *(float4*)&Xsd[(c*32+kk)*36 + q*4] = px[u];                          \
      } }

  SLOAD(0)
  for (int k0 = 0; k0 < 160; k0 += 32) {
    SSTORE()
    __syncthreads();
    if (k0 + 32 < 160) SLOAD(k0+32)
    #pragma unroll 4
    for (int k = 0; k < 32; ++k) {
      float4 a4 = *(float4*)&As[(k*17 + an)*4];
      float4 x0 = *(float4*)&Xsj[(0*32+k)*36 + h0];
      float4 x1 = *(float4*)&Xsj[(1*32+k)*36 + h0];
      float4 x2 = *(float4*)&Xsj[(2*32+k)*36 + h0];
      float4 x3 = *(float4*)&Xsj[(3*32+k)*36 + h0];
      float X0v[4]={x0.x,x0.y,x0.z,x0.w}, X1v[4]={x1.x,x1.y,x1.z,x1.w};
      float X2v[4]={x2.x,x2.y,x2.z,x2.w}, X3v[4]={x3.x,x3.y,x3.z,x3.w};
      #pragma unroll
      for (int j = 0; j < 4; ++j) {
        a0[j] += a4.x*X0v[j];
        aR[j] += a4.y*X1v[j] - a4.z*X2v[j];
        aI[j] += a4.y*X2v[j] + a4.z*X1v[j];
        a2[j] += a4.w*X3v[j];
      }
    }
    __syncthreads();
  }
  #undef SLOAD
  #undef SSTORE
  // write agg results c-packed: PsH[job] @ job*2112, layout [16n][33h][4c]
  float* PsH = smem + job*2112;
  #pragma unroll
  for (int j = 0; j < 4; ++j)
    *(float4*)&PsH[(an*33 + h0 + j)*4] = make_float4(a0[j], aR[j], aI[j], a2[j]);
}

// step1 transform pass: gates for one layer (16 rows = 16 nodes x batch b)
template<int KTOT, int KXA>
__device__ __forceinline__ void s1_pass(const float* __restrict__ Wraw,
    const float* __restrict__ bias, const float* __restrict__ hprev,
    float* __restrict__ Z, float* __restrict__ T1, float* __restrict__ Mf,
    const float* PsA, int stA, const float* PsB, int stB,
    float* Ws, int n0, int b, int tid) {
  const float4* Wg = (const float4*)Wraw;
  int og = tid & 31, rg = tid >> 5;
  float acc0[2][3]={{0,0,0},{0,0,0}}, accR[2][3]={{0,0,0},{0,0,0}};
  float accI[2][3]={{0,0,0},{0,0,0}}, acc2[2][3]={{0,0,0},{0,0,0}};
  constexpr int NCHK = KTOT/8;
  for (int cc = 0; cc < NCHK; ++cc) {
    __syncthreads();
    #pragma unroll
    for (int u = 0; u < 4; ++u) {
      int f = tid + u*256;
      int c = f >> 8, rem = f & 255, kk = rem >> 5, o = rem & 31;
      float4 v = Wg[((size_t)c*KTOT + cc*8 + kk)*32 + o];
      *(float4*)&Ws[((c*8+kk)*32 + o)*4] = v;
    }
    __syncthreads();
    const float* pb; int st, ko;
    if (cc*8 < KXA) { pb = PsA; st = stA; ko = 0; }
    else            { pb = PsB; st = stB; ko = KXA; }
    #pragma unroll 2
    for (int kk = 0; kk < 8; ++kk) {
      int k = cc*8 + kk;
      float4 w0 = *(float4*)&Ws[((0*8+kk)*32+og)*4];
      float4 w1 = *(float4*)&Ws[((1*8+kk)*32+og)*4];
      float4 w2 = *(float4*)&Ws[((2*8+kk)*32+og)*4];
      float4 w3 = *(float4*)&Ws[((3*8+kk)*32+og)*4];
      float W0v[3]={w0.x,w0.y,w0.z}, W1v[3]={w1.x,w1.y,w1.z};
      float W2v[3]={w2.x,w2.y,w2.z}, W3v[3]={w3.x,w3.y,w3.z};
      #pragma unroll
      for (int rr = 0; rr < 2; ++rr) {
        int r = rg*2 + rr;
        float4 p = *(const float4*)&pb[r*st + (k-ko)*4];
        #pragma unroll
        for (int q = 0; q < 3; ++q) {
          acc0[rr][q] += p.x*W0v[q];
          accR[rr][q] += p.y*W1v[q] - p.z*W2v[q];
          accI[rr][q] += p.y*W2v[q] + p.z*W1v[q];
          acc2[rr][q] += p.w*W3v[q];
        }
      }
    }
  }
  const float* bz = bias + (0*HH + og)*4;
  const float* br = bias + (1*HH + og)*4;
  const float* bh = bias + (2*HH + og)*4;
  float bzv[4] = {bz[0],bz[1],bz[2],bz[3]};
  float brv[4] = {br[0],br[1],br[2],br[3]};
  float bhv[4] = {bh[0],bh[1],bh[2],bh[3]};
  #pragma unroll
  for (int rr = 0; rr < 2; ++rr) {
    int n = n0 + rg*2 + rr;
    if (n >= NN) continue;
    int row = n*BB + b;
    float ys[3][4];
    #pragma unroll
    for (int q = 0; q < 3; ++q) {
      float Y0 = acc0[rr][q], Yr = accR[rr][q], Yi = accI[rr][q], Y2 = acc2[rr][q];
      ys[q][0] = 0.25f*(Y0 + 2.f*Yr + Y2);
      ys[q][1] = 0.25f*(Y0 - 2.f*Yi - Y2);
      ys[q][2] = 0.25f*(Y0 - 2.f*Yr + Y2);
      ys[q][3] = 0.25f*(Y0 + 2.f*Yi - Y2);
    }
    float4 z = make_float4(sigmoidf_(ys[0][0]+bzv[0]), sigmoidf_(ys[0][1]+bzv[1]),
                           sigmoidf_(ys[0][2]+bzv[2]), sigmoidf_(ys[0][3]+bzv[3]));
    *(float4*)&Z[((size_t)row*HH + og)*4] = z;
    float4 hp = *(const float4*)&hprev[((size_t)row*HH + og)*4];
    float m0 = sigmoidf_(ys[1][0]+brv[0]) * hp.x;
    float m1 = sigmoidf_(ys[1][1]+brv[1]) * hp.y;
    float m2 = sigmoidf_(ys[1][2]+brv[2]) * hp.z;
    float m3 = sigmoidf_(ys[1][3]+brv[3]) * hp.w;
    size_t mb = (size_t)row*HH + og;
    size_t cs = (size_t)ROWS*HH;
    Mf[mb]      = m0+m1+m2+m3;
    Mf[mb+cs]   = m0-m2;
    Mf[mb+2*cs] = m3-m1;
    Mf[mb+3*cs] = m0-m1+m2-m3;
    float4 tv = make_float4(ys[2][0]+bhv[0], ys[2][1]+bhv[1], ys[2][2]+bhv[2], ys[2][3]+bhv[3]);
    *(float4*)&T1[((size_t)row*HH + og)*4] = tv;
  }
}

struct S1Params {
  const float* adjF; const float* PINt;    // PINt: this t's split pair
  const float* H0F; const float* H1F;
  const float* WA0; const float* WA1;
  const float* B0; const float* B1;
  const float* H0; const float* H1;
  float* Z0; float* T10; float* M0F;
  float* Z1; float* T11; float* M1F;
};

__global__ __launch_bounds__(256,2) void k_step1(S1Params p) {
  __shared__ float smem[SMEM_STEP];
  int tid = threadIdx.x;
  int nt = blockIdx.x % 10, b = blockIdx.x / 10;
  int n0 = nt * 16;
  step_agg(p.adjF, p.H0F, p.H1F, n0, b, tid, smem);
  // stage PsIN [16n][16f][4c] @4224, summing split parts
  {
    int c = tid >> 6, rem = tid & 63, nl = rem >> 2, fq = rem & 3;
    float4 v = make_float4(0,0,0,0);
    if (n0 + nl < NN) {
      const float* a = p.PINt + ((size_t)c*NN + n0+nl)*NCIN + b*16 + fq*4;
      float4 va = *(const float4*)a;
      float4 vb = *(const float4*)(a + SZ_PIN);
      v = make_float4(va.x+vb.x, va.y+vb.y, va.z+vb.z, va.w+vb.w);
    }
    float* PsIN = smem + 4224;
    PsIN[(nl*16 + fq*4+0)*4 + c] = v.x;
    PsIN[(nl*16 + fq*4+1)*4 + c] = v.y;
    PsIN[(nl*16 + fq*4+2)*4 + c] = v.z;
    PsIN[(nl*16 + fq*4+3)*4 + c] = v.w;
  }
  float* Ws = smem + 5248;
  s1_pass<48,16>(p.WA0, p.B0, p.H0, p.Z0, p.T10, p.M0F,
                 smem + 4224, 64, smem, 132, Ws, n0, b, tid);
  s1_pass<64,32>(p.WA1, p.B1, p.H1, p.Z1, p.T11, p.M1F,
                 smem, 132, smem + 2112, 132, Ws, n0, b, tid);
}

// step2 transform pass: hidden update for one layer
__device__ __forceinline__ void s2_pass(const float* __restrict__ WBg,
    const float* __restrict__ T1g, const float* __restrict__ Zg,
    float* __restrict__ h, float* __restrict__ hf,
    float* __restrict__ outp, float* __restrict__ hlast, int t,
    const float* PsM, float* Ws, int n0, int b, int tid) {
  int og = tid & 31, rg = tid >> 5;
  __syncthreads();
  #pragma unroll
  for (int u = 0; u < 4; ++u) {
    int f = tid + u*256;
    ((float4*)Ws)[f] = ((const float4*)WBg)[f];
  }
  __syncthreads();
  float acc0[2]={0,0}, accR[2]={0,0}, accI[2]={0,0}, acc2[2]={0,0};
  #pragma unroll 4
  for (int k = 0; k < 32; ++k) {
    float4 w = *(const float4*)&Ws[(k*32 + og)*4];
    #pragma unroll
    for (int rr = 0; rr < 2; ++rr) {
      int r = rg*2 + rr;
      float4 pm = *(const float4*)&PsM[(r*33 + k)*4];
      acc0[rr] += pm.x*w.x;
      accR[rr] += pm.y*w.y - pm.z*w.z;
      accI[rr] += pm.y*w.z + pm.z*w.y;
      acc2[rr] += pm.w*w.w;
    }
  }
  #pragma unroll
  for (int rr = 0; rr < 2; ++rr) {
    int n = n0 + rg*2 + rr;
    if (n >= NN) continue;
    int row = n*BB + b;
    float y0 = 0.25f*(acc0[rr] + 2.f*accR[rr] + acc2[rr]);
    float y1 = 0.25f*(acc0[rr] - 2.f*accI[rr] - acc2[rr]);
    float y2 = 0.25f*(acc0[rr] - 2.f*accR[rr] + acc2[rr]);
    float y3 = 0.25f*(acc0[rr] + 2.f*accI[rr] - acc2[rr]);
    float4 t1 = *(const float4*)&T1g[((size_t)row*HH + og)*4];
    float h0v = tanhf(t1.x + y0);
    float h1v = tanhf(t1.y + y1);
    float h2v = tanhf(t1.z + y2);
    float h3v = tanhf(t1.w + y3);
    float4 z = *(const float4*)&Zg[((size_t)row*HH + og)*4];
    float4 hp = *(const float4*)&h[((size_t)row*HH + og)*4];
    float n0v = z.x*hp.x + (1.f-z.x)*h0v;
    float n1v = z.y*hp.y + (1.f-z.y)*h1v;
    float n2v = z.z*hp.z + (1.f-z.z)*h2v;
    float n3v = z.w*hp.w + (1.f-z.w)*h3v;
    *(float4*)&h[((size_t)row*HH + og)*4] = make_float4(n0v,n1v,n2v,n3v);
    size_t hb = (size_t)row*HH + og, cs = (size_t)ROWS*HH;
    hf[hb]      = n0v+n1v+n2v+n3v;
    hf[hb+cs]   = n0v-n2v;
    hf[hb+2*cs] = n3v-n1v;
    hf[hb+3*cs] = n0v-n1v+n2v-n3v;
    if (outp) {
      float* dst = outp + (((size_t)b*TT + t)*NN + n)*(HH*4) + og*4;
      *(float4*)dst = make_float4(n0v,n1v,n2v,n3v);
    }
    if (hlast) {
      float* dst = hlast + ((size_t)(b*NN + n))*(HH*4) + og*4;
      *(float4*)dst = make_float4(n0v,n1v,n2v,n3v);
    }
  }
}

struct S2Params {
  const float* adjF; const float* M0F; const float* M1F;
  const float* WB0; const float* WB1;
  const float* T10; const float* Z0; const float* T11; const float* Z1;
  float* H0; float* H1; float* H0F; float* H1F;
  float* outp; float* hlast0; float* hlast1;
  int t;
};

__global__ __launch_bounds__(256,2) void k_step2(S2Params p) {
  __shared__ float smem[SMEM_STEP];
  int tid = threadIdx.x;
  int nt = blockIdx.x % 10, b = blockIdx.x / 10;
  int n0 = nt * 16;
  step_agg(p.adjF, p.M0F, p.M1F, n0, b, tid, smem);
  float* Ws = smem + 4224;
  s2_pass(p.WB0, p.T10, p.Z0, p.H0, p.H0F, nullptr, p.hlast0, p.t, smem,        Ws, n0, b, tid);
  s2_pass(p.WB1, p.T11, p.Z1, p.H1, p.H1F, p.outp,  p.hlast1, p.t, smem + 2112, Ws, n0, b, tid);
}

extern "C" void kernel_launch(void* const* d_in, const int* in_sizes, int n_in,
                              void* d_out, int out_size, void* d_ws, size_t ws_size,
                              hipStream_t stream) {
  const float* inp  = (const float*)d_in[0];
  const float* U    = (const float*)d_in[1];
  const float* Wxz0 = (const float*)d_in[2];
  const float* Wxr0 = (const float*)d_in[3];
  const float* Wxh0 = (const float*)d_in[4];
  const float* Whz0 = (const float*)d_in[5];
  const float* Whr0 = (const float*)d_in[6];
  const float* B0   = (const float*)d_in[7];
  const float* Wxz1 = (const float*)d_in[8];
  const float* Wxr1 = (const float*)d_in[9];
  const float* Wxh1 = (const float*)d_in[10];
  const float* Whz1 = (const float*)d_in[11];
  const float* Whr1 = (const float*)d_in[12];
  const float* B1   = (const float*)d_in[13];
  float* out = (float*)d_out;

  float* ws = (float*)d_ws;
  float* ADJF = ws;  ws += SZ_ADJF;
  float* WA0  = ws;  ws += SZ_WA0;
  float* WA1  = ws;  ws += SZ_WA1;
  float* WB0  = ws;  ws += SZ_WB;
  float* WB1  = ws;  ws += SZ_WB;
  float* H0   = ws;  ws += SZ_STATE;
  float* H1   = ws;  ws += SZ_STATE;
  float* H0F  = ws;  ws += SZ_STATE;
  float* H1F  = ws;  ws += SZ_STATE;
  float* PIN  = ws;  ws += (size_t)TT*2*SZ_PIN;
  float* PH0  = ws;  ws += 2*SZ_STATE;
  float* M0F  = ws;  ws += SZ_STATE;
  float* M1F  = ws;  ws += SZ_STATE;
  float* Z0   = ws;  ws += SZ_STATE;
  float* Z1   = ws;  ws += SZ_STATE;
  float* T10  = ws;  ws += SZ_STATE;
  float* T11  = ws;  ws += SZ_STATE;

  k_pre<<<NN + (SZ_WA0+SZ_WA1+2*SZ_WB+255)/256, 256, 0, stream>>>(
      U, ADJF, Wxz0,Wxr0,Wxh0,Whz0,Whr0, Wxz1,Wxr1,Wxh1,Whz1,Whr1, WA0,WA1,WB0,WB1);

  // all input aggregations upfront (independent of recurrence)
  k_aggIN<<<TT*2*80, 256, 0, stream>>>(ADJF, inp, PIN);

  float* hlast0 = out + (size_t)BB*TT*NN*HH*4;
  float* hlast1 = hlast0 + (size_t)BB*NN*HH*4;

  // ---- t = 0 (zero hidden) ----
  {
    FAParams p;
    p.j[0] = FAJob{PIN, nullptr, WA0, B0, nullptr, Z0, T10, M0F, 1};
    p.j[1] = p.j[0];
    k_fusedA_L0<<<dim3(300,1), 256, 0, stream>>>(p);
  }
  {
    FBParams p;
    p.j[0] = FBJob{nullptr, WB0, T10, Z0, H0, H0F, nullptr, nullptr, 0, 1, 0};
    p.j[1] = p.j[0];
    k_fusedB<<<dim3(300,1), 256, 0, stream>>>(p);
  }
  {
    AggParams p; p.X0 = H0F; p.P0 = PH0; p.nb = 160;
    k_agg<<<320, 256, 0, stream>>>(p, ADJF);
  }
  {
    FAParams p;
    p.j[0] = FAJob{PIN, nullptr, WA0, B0, nullptr, Z0, T10, M0F, 1};
    p.j[1] = FAJob{PH0, nullptr, WA1, B1, nullptr, Z1, T11, M1F, 1};
    k_fusedA_L1<<<dim3(300,1), 256, 0, stream>>>(p);
  }
  {
    FBParams p;
    p.j[0] = FBJob{nullptr, WB1, T11, Z1, H1, H1F, out, nullptr, 0, 1, 1};
    p.j[1] = p.j[0];
    k_fusedB<<<dim3(300,1), 256, 0, stream>>>(p);
  }

  // ---- t = 1..7 : fused steps ----
  for (int t = 1; t < TT; ++t) {
    {
      S1Params p;
      p.adjF = ADJF; p.PINt = PIN + (size_t)t*2*SZ_PIN;
      p.H0F = H0F; p.H1F = H1F;
      p.WA0 = WA0; p.WA1 = WA1; p.B0 = B0; p.B1 = B1;
      p.H0 = H0; p.H1 = H1;
      p.Z0 = Z0; p.T10 = T10; p.M0F = M0F;
      p.Z1 = Z1; p.T11 = T11; p.M1F = M1F;
      k_step1<<<320, 256, 0, stream>>>(p);
    }
    {
      int last = (t == TT-1);
      S2Params p;
      p.adjF = ADJF; p.M0F = M0F; p.M1F = M1F;
      p.WB0 = WB0; p.WB1 = WB1;
      p.T10 = T10; p.Z0 = Z0; p.T11 = T11; p.Z1 = Z1;
      p.H0 = H0; p.H1 = H1; p.H0F = H0F; p.H1F = H1F;
      p.outp = out;
      p.hlast0 = last ? hlast0 : nullptr;
      p.hlast1 = last ? hlast1 : nullptr;
      p.t = t;
      k_step2<<<320, 256, 0, stream>>>(p);
    }
  }
}

// Round 8
// 815.232 us; speedup vs baseline: 1.2505x; 1.2505x over previous
//
#include <hip/hip_runtime.h>
#include <math.h>

// Problem constants
#define NN 150   // nodes
#define BB 32    // batch
#define TT 8     // time
#define FF 16    // input features
#define HH 32    // hidden
#define ROWS (NN*BB)     // 4800 (row index = n*32 + b)
#define NCIN (BB*FF)     // 512
#define NCH  (BB*HH)     // 1024
#define ADJ_LD 160       // padded adjacency row stride (zero-filled 150..159)
#define PS_LD 65         // fusedA Ps k-stride in float4 units

// workspace sizes (floats)
#define SZ_ADJF (4*NN*ADJ_LD)
#define SZ_WA0  (4*48*32*4)   // packed [c][48][32][4]
#define SZ_WA1  (4*64*32*4)   // packed [c][64][32][4]
#define SZ_WB   (32*32*4)     // packed [k][o][c]
#define SZ_STATE (ROWS*HH*4)  // 614400 ; also = partial stride 4*NN*NCH
#define SZ_PIN  (4*NN*NCIN)   // 307200 ; partial stride of input agg

__device__ __forceinline__ float sigmoidf_(float x){ return 1.f/(1.f+expf(-x)); }

__device__ __forceinline__ float comp_of4(float x0, float x1, float x2, float x3, int c) {
  return c==0 ? (x0+x1+x2+x3) : c==1 ? (x0-x2) : c==2 ? (x3-x1) : (x0-x1+x2-x3);
}

// Fourier comps of a real length-4 tube: c0, c1re, c1im, c2 (face3 = conj(face1))
// ifft: y0=(c0+2c1re+c2)/4; y1=(c0-2c1im-c2)/4; y2=(c0-2c1re+c2)/4; y3=(c0+2c1im-c2)/4

// ---------------- pre: adjacency (blocks 0..149) + packed weights ----------------
__global__ __launch_bounds__(256) void k_pre(
    const float* __restrict__ U, float* __restrict__ adjF,
    const float* __restrict__ Wxz0, const float* __restrict__ Wxr0, const float* __restrict__ Wxh0,
    const float* __restrict__ Whz0, const float* __restrict__ Whr0,
    const float* __restrict__ Wxz1, const float* __restrict__ Wxr1, const float* __restrict__ Wxh1,
    const float* __restrict__ Whz1, const float* __restrict__ Whr1,
    float* __restrict__ WA0p, float* __restrict__ WA1p,
    float* __restrict__ WB0p, float* __restrict__ WB1p) {
  __shared__ float Ufl[NN*16*4];
  __shared__ float Arow[NN*4];
  __shared__ float red[256];
  __shared__ float mxs[4], isms[4];
  int tid = threadIdx.x;
  if (blockIdx.x < NN) {
    int n = blockIdx.x;
    for (int idx = tid; idx < NN*16; idx += 256) {
      const float* s = U + (size_t)idx*4;
      float x0=s[0], x1=s[1], x2=s[2], x3=s[3];
      Ufl[idx*4+0] = x0+x1+x2+x3;
      Ufl[idx*4+1] = x0-x2;
      Ufl[idx*4+2] = x3-x1;
      Ufl[idx*4+3] = x0-x1+x2-x3;
    }
    __syncthreads();
    if (tid < NN) {
      int m = tid;
      float a0=0, ar=0, ai=0, a2=0;
      #pragma unroll
      for (int e = 0; e < 16; ++e) {
        const float* un = &Ufl[(n*16+e)*4];
        const float* um = &Ufl[(m*16+e)*4];
        a0 += un[0]*um[0];
        ar += un[1]*um[1] - un[2]*um[2];
        ai += un[1]*um[2] + un[2]*um[1];
        a2 += un[3]*um[3];
      }
      float r0 = 0.25f*(a0 + 2.f*ar + a2);
      float r1 = 0.25f*(a0 - 2.f*ai - a2);
      float r2 = 0.25f*(a0 - 2.f*ar + a2);
      float r3 = 0.25f*(a0 + 2.f*ai - a2);
      Arow[m*4+0] = fmaxf(r0, 0.f);
      Arow[m*4+1] = fmaxf(r1, 0.f);
      Arow[m*4+2] = fmaxf(r2, 0.f);
      Arow[m*4+3] = fmaxf(r3, 0.f);
    }
    __syncthreads();
    for (int r = 0; r < 4; ++r) {
      float v = (tid < NN) ? Arow[tid*4+r] : -1e30f;
      red[tid] = v; __syncthreads();
      for (int s = 128; s > 0; s >>= 1) { if (tid < s) red[tid] = fmaxf(red[tid], red[tid+s]); __syncthreads(); }
      if (tid == 0) mxs[r] = red[0];
      __syncthreads();
      float e = (tid < NN) ? expf(Arow[tid*4+r] - mxs[r]) : 0.f;
      red[tid] = e; __syncthreads();
      for (int s = 128; s > 0; s >>= 1) { if (tid < s) red[tid] += red[tid+s]; __syncthreads(); }
      if (tid == 0) isms[r] = 1.f / red[0];
      __syncthreads();
      if (tid < NN) Arow[tid*4+r] = e * isms[r];
      __syncthreads();
    }
    if (tid < NN) {
      int m = tid;
      float e0=Arow[m*4+0], e1=Arow[m*4+1], e2=Arow[m*4+2], e3=Arow[m*4+3];
      size_t base = (size_t)n*ADJ_LD + m;
      size_t cs = (size_t)NN*ADJ_LD;
      adjF[base]      = e0+e1+e2+e3;
      adjF[base+cs]   = e0-e2;
      adjF[base+2*cs] = e3-e1;
      adjF[base+3*cs] = e0-e1+e2-e3;
    } else if (tid < ADJ_LD) {
      size_t base = (size_t)n*ADJ_LD + tid;
      size_t cs = (size_t)NN*ADJ_LD;
      adjF[base] = 0.f; adjF[base+cs] = 0.f; adjF[base+2*cs] = 0.f; adjF[base+3*cs] = 0.f;
    }
    return;
  }
  int idx = (blockIdx.x - NN)*256 + tid;
  const float* src = nullptr;
  float* dst; int didx; int c;
  if (idx < SZ_WA0) {
    c = idx / 6144;
    int rem = idx % 6144;
    int k = rem >> 7, og = (rem >> 2) & 31, q = rem & 3;
    if (q == 0) src = (k < FF) ? Wxz0 + ((size_t)k*HH + og)*4 : Whz0 + ((size_t)(k-FF)*HH + og)*4;
    else if (q == 1) src = (k < FF) ? Wxr0 + ((size_t)k*HH + og)*4 : Whr0 + ((size_t)(k-FF)*HH + og)*4;
    else if (q == 2 && k < FF) src = Wxh0 + ((size_t)k*HH + og)*4;
    dst = WA0p; didx = idx;
  } else if (idx < SZ_WA0 + SZ_WA1) {
    int id = idx - SZ_WA0;
    c = id >> 13;
    int rem = id & 8191;
    int k = rem >> 7, og = (rem >> 2) & 31, q = rem & 3;
    if (q == 0) src = (k < HH) ? Wxz1 + ((size_t)k*HH + og)*4 : Whz1 + ((size_t)(k-HH)*HH + og)*4;
    else if (q == 1) src = (k < HH) ? Wxr1 + ((size_t)k*HH + og)*4 : Whr1 + ((size_t)(k-HH)*HH + og)*4;
    else if (q == 2 && k < HH) src = Wxh1 + ((size_t)k*HH + og)*4;
    dst = WA1p; didx = id;
  } else if (idx < SZ_WA0 + SZ_WA1 + SZ_WB) {
    int id = idx - (SZ_WA0 + SZ_WA1);
    int k = id >> 7, o = (id >> 2) & 31;
    c = id & 3;
    src = Whr0 + ((size_t)k*HH + o)*4;
    dst = WB0p; didx = id;
  } else if (idx < SZ_WA0 + SZ_WA1 + 2*SZ_WB) {
    int id = idx - (SZ_WA0 + SZ_WA1 + SZ_WB);
    int k = id >> 7, o = (id >> 2) & 31;
    c = id & 3;
    src = Whr1 + ((size_t)k*HH + o)*4;
    dst = WB1p; didx = id;
  } else return;
  float v0=0,v1=0,v2=0,v3=0;
  if (src) { v0=src[0]; v1=src[1]; v2=src[2]; v3=src[3]; }
  dst[didx] = comp_of4(v0,v1,v2,v3,c);
}

// ---------------- agg body (split-K; n0/col0 passed directly for XCD swizzle) ----------------
template<bool RAW>
__device__ __forceinline__ void agg_body(const float* __restrict__ adjF,
                                         const float* __restrict__ X,
                                         const float* __restrict__ inp,
                                         float* __restrict__ P, int ncol,
                                         int n0, int col0, int part, int rawt,
                                         float* As, float* Xs, int tid) {
  int kbeg = part ? 96 : 0;
  int kend = part ? NN : 96;
  int ti = tid & 31, tj = tid >> 5;
  int j0 = tj * 4;
  float a0[4]={}, aR[4]={}, aI[4]={}, a2v[4]={};
  float4 pa[4], px[4];

  #define LOAD_A(K0)                                                         \
    _Pragma("unroll")                                                        \
    for (int u = 0; u < 4; ++u) {                                            \
      int e = tid + u*256;                                                   \
      int c = e >> 8, rem = e & 255, i = rem >> 3, kq = rem & 7;             \
      int nn_ = n0 + i;                                                      \
      pa[u] = make_float4(0,0,0,0);                                          \
      if (nn_ < NN) pa[u] = *(const float4*)(adjF + ((size_t)c*NN + nn_)*ADJ_LD + (K0) + kq*4); \
    }
  #define STORE_A()                                                          \
    _Pragma("unroll")                                                        \
    for (int u = 0; u < 4; ++u) {                                            \
      int e = tid + u*256;                                                   \
      int c = e >> 8, rem = e & 255, i = rem >> 3, kq = rem & 7;             \
      As[((kq*4+0)*33 + i)*4 + c] = pa[u].x;                                 \
      As[((kq*4+1)*33 + i)*4 + c] = pa[u].y;                                 \
      As[((kq*4+2)*33 + i)*4 + c] = pa[u].z;                                 \
      As[((kq*4+3)*33 + i)*4 + c] = pa[u].w;                                 \
    }
  #define LOAD_X(K0)                                                         \
    if (RAW) {                                                               \
      int q = tid & 7, kk = tid >> 3;                                        \
      int mm = (K0) + kk;                                                    \
      int col = col0 + q*4;                                                  \
      int b = col >> 4, f = col & 15;                                        \
      px[0]=px[1]=px[2]=px[3]=make_float4(0,0,0,0);                          \
      if (mm < NN) {                                                         \
        const float* s = inp + (((size_t)(b*TT + rawt)*NN + mm)*FF + f)*4;   \
        px[0] = *(const float4*)(s+0);                                       \
        px[1] = *(const float4*)(s+4);                                       \
        px[2] = *(const float4*)(s+8);                                       \
        px[3] = *(const float4*)(s+12);                                      \
      }                                                                      \
    } else {                                                                 \
      _Pragma("unroll")                                                      \
      for (int u = 0; u < 4; ++u) {                                          \
        int e = tid + u*256;                                                 \
        int c = e >> 8, rem = e & 255, kk = rem >> 3, q = rem & 7;           \
        int mm = (K0) + kk;                                                  \
        px[u] = make_float4(0,0,0,0);                                        \
        if (mm < NN) px[u] = *(const float4*)(X + ((size_t)c*NN + mm)*ncol + col0 + q*4); \
      }                                                                      \
    }
  #define STORE_X()                                                          \
    if (RAW) {                                                               \
      int q = tid & 7, kk = tid >> 3;                                        \
      float4 r0 = px[0], r1 = px[1], r2 = px[2], r3 = px[3];                 \
      float4 w;                                                              \
      w = make_float4(r0.x+r0.y+r0.z+r0.w, r1.x+r1.y+r1.z+r1.w, r2.x+r2.y+r2.z+r2.w, r3.x+r3.y+r3.z+r3.w); \
      *(float4*)&Xs[(0*32+kk)*36 + q*4] = w;                                 \
      w = make_float4(r0.x-r0.z, r1.x-r1.z, r2.x-r2.z, r3.x-r3.z);           \
      *(float4*)&Xs[(1*32+kk)*36 + q*4] = w;                                 \
      w = make_float4(r0.w-r0.y, r1.w-r1.y, r2.w-r2.y, r3.w-r3.y);           \
      *(float4*)&Xs[(2*32+kk)*36 + q*4] = w;                                 \
      w = make_float4(r0.x-r0.y+r0.z-r0.w, r1.x-r1.y+r1.z-r1.w, r2.x-r2.y+r2.z-r2.w, r3.x-r3.y+r3.z-r3.w); \
      *(float4*)&Xs[(3*32+kk)*36 + q*4] = w;                                 \
    } else {                                                                 \
      _Pragma("unroll")                                                      \
      for (int u = 0; u < 4; ++u) {                                          \
        int e = tid + u*256;                                                 \
        int c = e >> 8, rem = e & 255, kk = rem >> 3, q = rem & 7;           \
        *(float4*)&Xs[(c*32+kk)*36 + q*4] = px[u];                           \
      }                                                                      \
    }

  LOAD_A(kbeg)
  LOAD_X(kbeg)
  for (int k0 = kbeg; k0 < kend; k0 += 32) {
    STORE_A()
    STORE_X()
    __syncthreads();
    int k0n = k0 + 32;
    if (k0n < kend) {
      LOAD_A(k0n)
      LOAD_X(k0n)
    }
    #pragma unroll 4
    for (int k = 0; k < 32; ++k) {
      float4 a4 = *(float4*)&As[(k*33 + ti)*4];
      float4 x0 = *(float4*)&Xs[(0*32+k)*36 + j0];
      float4 x1 = *(float4*)&Xs[(1*32+k)*36 + j0];
      float4 x2 = *(float4*)&Xs[(2*32+k)*36 + j0];
      float4 x3 = *(float4*)&Xs[(3*32+k)*36 + j0];
      float X0v[4]={x0.x,x0.y,x0.z,x0.w}, X1v[4]={x1.x,x1.y,x1.z,x1.w};
      float X2v[4]={x2.x,x2.y,x2.z,x2.w}, X3v[4]={x3.x,x3.y,x3.z,x3.w};
      #pragma unroll
      for (int j = 0; j < 4; ++j) {
        a0[j]  += a4.x*X0v[j];
        aR[j]  += a4.y*X1v[j] - a4.z*X2v[j];
        aI[j]  += a4.y*X2v[j] + a4.z*X1v[j];
        a2v[j] += a4.w*X3v[j];
      }
    }
    __syncthreads();
  }
  #undef LOAD_A
  #undef STORE_A
  #undef LOAD_X
  #undef STORE_X
  int nn_ = n0 + ti;
  if (nn_ < NN) {
    size_t cs = (size_t)NN*ncol;
    size_t rb = (size_t)nn_*ncol + col0 + j0;
    *(float4*)&P[rb]      = make_float4(a0[0],a0[1],a0[2],a0[3]);
    *(float4*)&P[rb+cs]   = make_float4(aR[0],aR[1],aR[2],aR[3]);
    *(float4*)&P[rb+2*cs] = make_float4(aI[0],aI[1],aI[2],aI[3]);
    *(float4*)&P[rb+3*cs] = make_float4(a2v[0],a2v[1],a2v[2],a2v[3]);
  }
}

#define AGG_AS 4224   // 32*33*4
#define AGG_XS 4608   // 4*32*36

// input aggregation for ALL timesteps, XCD-swizzled:
// combo (t,ct): 128 combos, xcd = combo%8; 10 blocks/combo (5 ntile x 2 part).
__global__ __launch_bounds__(256,4) void k_aggIN(const float* __restrict__ adjF,
                                                 const float* __restrict__ inp,
                                                 float* __restrict__ PIN) {
  __shared__ float As[AGG_AS];
  __shared__ float Xs[AGG_XS];
  int bid = blockIdx.x;
  int x = bid & 7, g = bid >> 3;            // g: 0..159
  int combo = x + 8*(g & 15);               // 0..127
  int idx = g >> 4;                         // 0..9
  int ntile = idx % 5, part = idx / 5;
  int t = combo >> 4, ct = combo & 15;
  float* P = PIN + (size_t)t*2*SZ_PIN + (size_t)part*SZ_PIN;
  agg_body<true>(adjF, nullptr, inp, P, NCIN, ntile*32, ct*32, part, t, As, Xs, threadIdx.x);
}

// hidden/M aggregation, XCD-swizzled.
// combo (job,ct): njobs*32 combos, xcd = combo%8; 10 blocks/combo.
struct AggParams {
  const float* X0; const float* X1;
  float* P0; float* P1;
  int njobs;    // grid = njobs*320
};
__global__ __launch_bounds__(256,4) void k_agg(AggParams pr, const float* __restrict__ adjF) {
  __shared__ float As[AGG_AS];
  __shared__ float Xs[AGG_XS];
  int bid = blockIdx.x;
  int ncombo = pr.njobs * 32;
  int cpx = ncombo >> 3;                    // combos per xcd: 4 (njobs=1) or 8 (njobs=2)
  int x = bid & 7, g = bid >> 3;
  int combo = x + 8*(g % cpx);
  int idx = g / cpx;                        // 0..9
  int ntile = idx % 5, part = idx / 5;
  int job = combo >> 5, ct = combo & 31;
  const float* X = job ? pr.X1 : pr.X0;
  float* P = (job ? pr.P1 : pr.P0) + (size_t)part * SZ_STATE;
  agg_body<false>(adjF, X, nullptr, P, NCH, ntile*32, ct*32, part, -1, As, Xs, threadIdx.x);
}

// ---------------- phase A: transform + gates -> Z, T1, Mf ----------------
struct FAJob {
  const float* Px; const float* Ph; const float* W; const float* bias;
  const float* hprev;
  float* Z; float* T1; float* Mf;
  int zh;
};
struct FAParams { FAJob j[2]; };

template<int KTOT, int KX>
__device__ __forceinline__ void fusedA_body(const FAJob& jb, float* Ps, float* Ws) {
  const int row0 = blockIdx.x * 16;
  const int tid = threadIdx.x;
  const int og = tid & 31;
  const int rg = tid >> 5;
  const int r0 = rg*2, r1 = rg*2 + 1;
  const size_t psx = (size_t)4*ROWS*KX;
  const size_t psh = (size_t)4*ROWS*HH;
  constexpr int K4 = KTOT/4;
  for (int e = tid; e < 16*4*K4; e += 256) {
    int k4 = e % K4; int c = (e / K4) & 3; int r = e / (K4*4);
    int k = k4*4;
    int row = row0 + r;
    float4 v;
    if (k < KX) {
      const float* a = &jb.Px[((size_t)c*ROWS + row)*KX + k];
      float4 va = *(const float4*)a;
      float4 vb = *(const float4*)(a + psx);
      v = make_float4(va.x+vb.x, va.y+vb.y, va.z+vb.z, va.w+vb.w);
    } else if (jb.zh) {
      v = make_float4(0,0,0,0);
    } else {
      const float* a = &jb.Ph[((size_t)c*ROWS + row)*HH + (k - KX)];
      float4 va = *(const float4*)a;
      float4 vb = *(const float4*)(a + psh);
      v = make_float4(va.x+vb.x, va.y+vb.y, va.z+vb.z, va.w+vb.w);
    }
    Ps[(r*PS_LD + k+0)*4 + c] = v.x;
    Ps[(r*PS_LD + k+1)*4 + c] = v.y;
    Ps[(r*PS_LD + k+2)*4 + c] = v.z;
    Ps[(r*PS_LD + k+3)*4 + c] = v.w;
  }
  float acc0[2][3]={{0,0,0},{0,0,0}}, accR[2][3]={{0,0,0},{0,0,0}};
  float accI[2][3]={{0,0,0},{0,0,0}}, acc2[2][3]={{0,0,0},{0,0,0}};
  constexpr int NCHK = KTOT/16;
  const float4* Wg = (const float4*)jb.W;
  for (int cc = 0; cc < NCHK; ++cc) {
    __syncthreads();
    #pragma unroll
    for (int u = 0; u < 8; ++u) {
      int f = tid + u*256;
      int c = f >> 9, rem = f & 511;
      float4 v = Wg[((size_t)c*KTOT + cc*16)*32 + rem];
      *(float4*)&Ws[((size_t)c*512 + rem)*4] = v;
    }
    __syncthreads();
    #pragma unroll 4
    for (int kk = 0; kk < 16; ++kk) {
      int k = cc*16 + kk;
      float4 pA = *(float4*)&Ps[(r0*PS_LD + k)*4];
      float4 pB = *(float4*)&Ps[(r1*PS_LD + k)*4];
      float4 w0 = *(float4*)&Ws[((0*16+kk)*32+og)*4];
      float4 w1 = *(float4*)&Ws[((1*16+kk)*32+og)*4];
      float4 w2 = *(float4*)&Ws[((2*16+kk)*32+og)*4];
      float4 w3 = *(float4*)&Ws[((3*16+kk)*32+og)*4];
      float W0v[3]={w0.x,w0.y,w0.z}, W1v[3]={w1.x,w1.y,w1.z};
      float W2v[3]={w2.x,w2.y,w2.z}, W3v[3]={w3.x,w3.y,w3.z};
      #pragma unroll
      for (int q = 0; q < 3; ++q) {
        acc0[0][q] += pA.x*W0v[q];
        acc0[1][q] += pB.x*W0v[q];
        accR[0][q] += pA.y*W1v[q] - pA.z*W2v[q];
        accR[1][q] += pB.y*W1v[q] - pB.z*W2v[q];
        accI[0][q] += pA.y*W2v[q] + pA.z*W1v[q];
        accI[1][q] += pB.y*W2v[q] + pB.z*W1v[q];
        acc2[0][q] += pA.w*W3v[q];
        acc2[1][q] += pB.w*W3v[q];
      }
    }
  }
  const float* bz = jb.bias + (0*HH + og)*4;
  const float* br = jb.bias + (1*HH + og)*4;
  const float* bh = jb.bias + (2*HH + og)*4;
  float bzv[4] = {bz[0],bz[1],bz[2],bz[3]};
  float brv[4] = {br[0],br[1],br[2],br[3]};
  float bhv[4] = {bh[0],bh[1],bh[2],bh[3]};
  #pragma unroll
  for (int rr = 0; rr < 2; ++rr) {
    int row = row0 + rg*2 + rr;
    float ys[3][4];
    #pragma unroll
    for (int q = 0; q < 3; ++q) {
      float Y0 = acc0[rr][q], Yr = accR[rr][q], Yi = accI[rr][q], Y2 = acc2[rr][q];
      ys[q][0] = 0.25f*(Y0 + 2.f*Yr + Y2);
      ys[q][1] = 0.25f*(Y0 - 2.f*Yi - Y2);
      ys[q][2] = 0.25f*(Y0 - 2.f*Yr + Y2);
      ys[q][3] = 0.25f*(Y0 + 2.f*Yi - Y2);
    }
    float4 z = make_float4(sigmoidf_(ys[0][0]+bzv[0]), sigmoidf_(ys[0][1]+bzv[1]),
                           sigmoidf_(ys[0][2]+bzv[2]), sigmoidf_(ys[0][3]+bzv[3]));
    *(float4*)&jb.Z[((size_t)row*HH + og)*4] = z;
    float4 hp = make_float4(0,0,0,0);
    if (!jb.zh) hp = *(const float4*)&jb.hprev[((size_t)row*HH + og)*4];
    float m0 = sigmoidf_(ys[1][0]+brv[0]) * hp.x;
    float m1 = sigmoidf_(ys[1][1]+brv[1]) * hp.y;
    float m2 = sigmoidf_(ys[1][2]+brv[2]) * hp.z;
    float m3 = sigmoidf_(ys[1][3]+brv[3]) * hp.w;
    size_t mb = (size_t)row*HH + og;
    size_t cs = (size_t)ROWS*HH;
    jb.Mf[mb]      = m0+m1+m2+m3;
    jb.Mf[mb+cs]   = m0-m2;
    jb.Mf[mb+2*cs] = m3-m1;
    jb.Mf[mb+3*cs] = m0-m1+m2-m3;
    float4 tv = make_float4(ys[2][0]+bhv[0], ys[2][1]+bhv[1], ys[2][2]+bhv[2], ys[2][3]+bhv[3]);
    *(float4*)&jb.T1[((size_t)row*HH + og)*4] = tv;
  }
}

#define FA_PS (16*PS_LD*4)

__global__ __launch_bounds__(256,3) void k_fusedA_both(FAParams pr) {
  __shared__ float Ps[FA_PS];
  __shared__ float Ws[8192];
  if (blockIdx.y == 0) fusedA_body<48,16>(pr.j[0], Ps, Ws);
  else                 fusedA_body<64,32>(pr.j[1], Ps, Ws);
}
__global__ __launch_bounds__(256,3) void k_fusedA_L0(FAParams pr) {
  __shared__ float Ps[FA_PS];
  __shared__ float Ws[8192];
  fusedA_body<48,16>(pr.j[0], Ps, Ws);
}
__global__ __launch_bounds__(256,3) void k_fusedA_L1(FAParams pr) {
  __shared__ float Ps[FA_PS];
  __shared__ float Ws[8192];
  fusedA_body<64,32>(pr.j[1], Ps, Ws);
}

// ---------------- phase B: Ht=tanh(T1+ifft(Pm.W)); Hnew=Z*Hprev+(1-Z)*Ht ----------------
struct FBJob {
  const float* Pm; const float* W; const float* T1; const float* Z;
  float* h; float* hf; float* outp; float* hlast;
  int t, zh, wout;
};
struct FBParams { FBJob j[2]; };
__global__ __launch_bounds__(256,4) void k_fusedB(FBParams pr) {
  __shared__ float Ps[16*32*4];
  __shared__ float Ws[32*32*4];
  FBJob jb = pr.j[blockIdx.y];
  int row0 = blockIdx.x * 16;
  int tid = threadIdx.x;
  int rg = tid >> 5, o = tid & 31;
  int r0 = rg*2, r1 = r0 + 1;
  float acc0[2]={0,0}, accR[2]={0,0}, accI[2]={0,0}, acc2[2]={0,0};
  if (!jb.zh) {
    #pragma unroll
    for (int u = 0; u < 4; ++u) {
      int f = tid + u*256;
      ((float4*)Ws)[f] = ((const float4*)jb.W)[f];
    }
    const size_t psh = (size_t)4*ROWS*HH;
    #pragma unroll
    for (int u = 0; u < 2; ++u) {
      int e = tid + u*256;
      int r = e >> 5, k = e & 31;
      int row = row0 + r;
      float4 v;
      float* vv = (float*)&v;
      #pragma unroll
      for (int c = 0; c < 4; ++c) {
        size_t ix = ((size_t)c*ROWS + row)*HH + k;
        vv[c] = jb.Pm[ix] + jb.Pm[ix + psh];
      }
      *(float4*)&Ps[(r*32 + k)*4] = v;
    }
    __syncthreads();
    #pragma unroll 8
    for (int k = 0; k < 32; ++k) {
      float4 pA = *(const float4*)&Ps[(r0*32 + k)*4];
      float4 pB = *(const float4*)&Ps[(r1*32 + k)*4];
      float4 w  = *(const float4*)&Ws[(k*32 + o)*4];
      acc0[0] += pA.x*w.x;  acc0[1] += pB.x*w.x;
      accR[0] += pA.y*w.y - pA.z*w.z;  accR[1] += pB.y*w.y - pB.z*w.z;
      accI[0] += pA.y*w.z + pA.z*w.y;  accI[1] += pB.y*w.z + pB.z*w.y;
      acc2[0] += pA.w*w.w;  acc2[1] += pB.w*w.w;
    }
  }
  #pragma unroll
  for (int rr = 0; rr < 2; ++rr) {
    int row = row0 + rg*2 + rr;
    float y0 = 0.25f*(acc0[rr] + 2.f*accR[rr] + acc2[rr]);
    float y1 = 0.25f*(acc0[rr] - 2.f*accI[rr] - acc2[rr]);
    float y2 = 0.25f*(acc0[rr] - 2.f*accR[rr] + acc2[rr]);
    float y3 = 0.25f*(acc0[rr] + 2.f*accI[rr] - acc2[rr]);
    float4 t1 = *(const float4*)&jb.T1[((size_t)row*HH + o)*4];
    float h0v = tanhf(t1.x + y0);
    float h1v = tanhf(t1.y + y1);
    float h2v = tanhf(t1.z + y2);
    float h3v = tanhf(t1.w + y3);
    float4 z = *(const float4*)&jb.Z[((size_t)row*HH + o)*4];
    float4 hp = make_float4(0,0,0,0);
    if (!jb.zh) hp = *(const float4*)&jb.h[((size_t)row*HH + o)*4];
    float n0v = z.x*hp.x + (1.f-z.x)*h0v;
    float n1v = z.y*hp.y + (1.f-z.y)*h1v;
    float n2v = z.z*hp.z + (1.f-z.z)*h2v;
    float n3v = z.w*hp.w + (1.f-z.w)*h3v;
    *(float4*)&jb.h[((size_t)row*HH + o)*4] = make_float4(n0v,n1v,n2v,n3v);
    size_t hb = (size_t)row*HH + o, cs = (size_t)ROWS*HH;
    jb.hf[hb]      = n0v+n1v+n2v+n3v;
    jb.hf[hb+cs]   = n0v-n2v;
    jb.hf[hb+2*cs] = n3v-n1v;
    jb.hf[hb+3*cs] = n0v-n1v+n2v-n3v;
    int n = row >> 5, b = row & 31;
    if (jb.wout) {
      float* dst = jb.outp + (((size_t)b*TT + jb.t)*NN + n)*(HH*4) + o*4;
      *(float4*)dst = make_float4(n0v,n1v,n2v,n3v);
    }
    if (jb.hlast) {
      float* dst = jb.hlast + ((size_t)(b*NN + n))*(HH*4) + o*4;
      *(float4*)dst = make_float4(n0v,n1v,n2v,n3v);
    }
  }
}

extern "C" void kernel_launch(void* const* d_in, const int* in_sizes, int n_in,
                              void* d_out, int out_size, void* d_ws, size_t ws_size,
                              hipStream_t stream) {
  const float* inp  = (const float*)d_in[0];
  const float* U    = (const float*)d_in[1];
  const float* Wxz0 = (const float*)d_in[2];
  const float* Wxr0 = (const float*)d_in[3];
  const float* Wxh0 = (const float*)d_in[4];
  const float* Whz0 = (const float*)d_in[5];
  const float* Whr0 = (const float*)d_in[6];
  const float* B0   = (const float*)d_in[7];
  const float* Wxz1 = (const float*)d_in[8];
  const float* Wxr1 = (const float*)d_in[9];
  const float* Wxh1 = (const float*)d_in[10];
  const float* Whz1 = (const float*)d_in[11];
  const float* Whr1 = (const float*)d_in[12];
  const float* B1   = (const float*)d_in[13];
  float* out = (float*)d_out;

  float* ws = (float*)d_ws;
  float* ADJF = ws;  ws += SZ_ADJF;
  float* WA0  = ws;  ws += SZ_WA0;
  float* WA1  = ws;  ws += SZ_WA1;
  float* WB0  = ws;  ws += SZ_WB;
  float* WB1  = ws;  ws += SZ_WB;
  float* H0   = ws;  ws += SZ_STATE;
  float* H1   = ws;  ws += SZ_STATE;
  float* H0F  = ws;  ws += SZ_STATE;
  float* H1F  = ws;  ws += SZ_STATE;
  float* PIN  = ws;  ws += (size_t)TT*2*SZ_PIN;
  float* PH0  = ws;  ws += 2*SZ_STATE;
  float* PH1  = ws;  ws += 2*SZ_STATE;
  float* PM0  = ws;  ws += 2*SZ_STATE;
  float* PM1  = ws;  ws += 2*SZ_STATE;
  float* M0F  = ws;  ws += SZ_STATE;
  float* M1F  = ws;  ws += SZ_STATE;
  float* Z0   = ws;  ws += SZ_STATE;
  float* Z1   = ws;  ws += SZ_STATE;
  float* T10  = ws;  ws += SZ_STATE;
  float* T11  = ws;  ws += SZ_STATE;

  k_pre<<<NN + (SZ_WA0+SZ_WA1+2*SZ_WB+255)/256, 256, 0, stream>>>(
      U, ADJF, Wxz0,Wxr0,Wxh0,Whz0,Whr0, Wxz1,Wxr1,Wxh1,Whz1,Whr1, WA0,WA1,WB0,WB1);

  // all input aggregations upfront (independent of recurrence)
  k_aggIN<<<TT*2*80, 256, 0, stream>>>(ADJF, inp, PIN);

  float* hlast0 = out + (size_t)BB*TT*NN*HH*4;
  float* hlast1 = hlast0 + (size_t)BB*NN*HH*4;

  // ---- t = 0 (zero hidden) ----
  {
    FAParams p;
    p.j[0] = FAJob{PIN, nullptr, WA0, B0, nullptr, Z0, T10, M0F, 1};
    p.j[1] = p.j[0];
    k_fusedA_L0<<<dim3(300,1), 256, 0, stream>>>(p);
  }
  {
    FBParams p;
    p.j[0] = FBJob{nullptr, WB0, T10, Z0, H0, H0F, nullptr, nullptr, 0, 1, 0};
    p.j[1] = p.j[0];
    k_fusedB<<<dim3(300,1), 256, 0, stream>>>(p);
  }
  {
    AggParams p; p.X0 = H0F; p.P0 = PH0; p.X1 = nullptr; p.P1 = nullptr; p.njobs = 1;
    k_agg<<<320, 256, 0, stream>>>(p, ADJF);
  }
  {
    FAParams p;
    p.j[0] = FAJob{PIN, nullptr, WA0, B0, nullptr, Z0, T10, M0F, 1};
    p.j[1] = FAJob{PH0, nullptr, WA1, B1, nullptr, Z1, T11, M1F, 1};
    k_fusedA_L1<<<dim3(300,1), 256, 0, stream>>>(p);
  }
  {
    FBParams p;
    p.j[0] = FBJob{nullptr, WB1, T11, Z1, H1, H1F, out, nullptr, 0, 1, 1};
    p.j[1] = p.j[0];
    k_fusedB<<<dim3(300,1), 256, 0, stream>>>(p);
  }

  // ---- t = 1..7 ----
  for (int t = 1; t < TT; ++t) {
    {
      AggParams p; p.X0 = H0F; p.P0 = PH0; p.X1 = H1F; p.P1 = PH1; p.njobs = 2;
      k_agg<<<640, 256, 0, stream>>>(p, ADJF);
    }
    {
      FAParams p;
      p.j[0] = FAJob{PIN + (size_t)t*2*SZ_PIN, PH0, WA0, B0, H0, Z0, T10, M0F, 0};
      p.j[1] = FAJob{PH0, PH1, WA1, B1, H1, Z1, T11, M1F, 0};
      k_fusedA_both<<<dim3(300,2), 256, 0, stream>>>(p);
    }
    {
      AggParams p; p.X0 = M0F; p.P0 = PM0; p.X1 = M1F; p.P1 = PM1; p.njobs = 2;
      k_agg<<<640, 256, 0, stream>>>(p, ADJF);
    }
    {
      int last = (t == TT-1);
      FBParams p;
      p.j[0] = FBJob{PM0, WB0, T10, Z0, H0, H0F, nullptr, last ? hlast0 : nullptr, t, 0, 0};
      p.j[1] = FBJob{PM1, WB1, T11, Z1, H1, H1F, out,     last ? hlast1 : nullptr, t, 0, 1};
      k_fusedB<<<dim3(300,2), 256, 0, stream>>>(p);
    }
  }
}